// Round 7
// baseline (4475.381 us; speedup 1.0000x reference)
//
#include <hip/hip_runtime.h>
#include <math.h>

constexpr int B = 24, HH = 8;
constexpr int NN = 256, MQ = 64;
constexpr int EC = 364;

#define PI_2 1.5707963267948966f

// ---------------- positional encoding table: tab[d*256+l] ----------------
__global__ void k_postab(float* __restrict__ tab) {
  int d = blockIdx.x, l = threadIdx.x;
  float fr = ((d & 1) == 0) ? powf(10000.f, -(float)d / 64.f)
                            : -powf(10000.f, -(float)(d - 1) / 64.f);
  float ph = (d & 1) ? PI_2 : 0.f;
  tab[d * 256 + l] = sinf(sinf((float)l * fr + ph));
}

__global__ void k_posadd(float* __restrict__ x, const float* __restrict__ tab, int L) {
  int i = blockIdx.x * 256 + threadIdx.x;
  if (i >= B * 64 * L) return;
  int l = i % L, d = (i / L) & 63;
  x[i] += tab[d * 256 + l];
}

// ---------------- norm over sequence axis (ddof=1, (sqrt(var)+eps)) -------
__global__ void k_norm(const float* __restrict__ x, float* __restrict__ y, int L) {
  int row = blockIdx.x;
  const float* xr = x + (size_t)row * L;
  float* yr = y + (size_t)row * L;
  int t = threadIdx.x;
  float s = 0.f;
  for (int l = t; l < L; l += 64) s += xr[l];
#pragma unroll
  for (int o = 32; o > 0; o >>= 1) s += __shfl_xor(s, o);
  float mu = s / (float)L;
  float ss = 0.f;
  for (int l = t; l < L; l += 64) { float dd = xr[l] - mu; ss += dd * dd; }
#pragma unroll
  for (int o = 32; o > 0; o >>= 1) ss += __shfl_xor(ss, o);
  float inv = 1.f / (sqrtf(ss / (float)(L - 1)) + 1e-6f);
  for (int l = t; l < L; l += 64) yr[l] = (xr[l] - mu) * inv;
}

// ---------------- depthwise conv1d ----------------------------------------
template<int K>
__global__ void k_dwconv(const float* __restrict__ x, float* __restrict__ y,
                         const float* __restrict__ w, int L) {
  int i = blockIdx.x * 256 + threadIdx.x;
  if (i >= B * 64 * L) return;
  int l = i % L, c = (i / L) % 64;
  const float* xr = x + (size_t)(i - l);
  float acc = 0.f;
#pragma unroll
  for (int k = 0; k < K; ++k) {
    int ll = l + k - K / 2;
    if (ll >= 0 && ll < L) acc += xr[ll] * w[c * K + k];
  }
  y[i] = acc;
}

// ---- out[b,o,l] = (res) + act(sum_c W[o,c]*A[b,c,l]), CIN=64 -------------
template<bool RELU, bool RES, bool PERB>
__global__ __launch_bounds__(256) void k_matmul(
    const float* __restrict__ A, const float* __restrict__ W,
    const float* res, float* out, int L) {
  __shared__ float sA[64 * 64];
  __shared__ float sW[64 * 64];
  int b = blockIdx.x, lt = blockIdx.y * 64;
  const float* Ab = A + (size_t)b * 64 * L;
  const float* Wb = W + (PERB ? (size_t)b * 4096 : 0);
  for (int i = threadIdx.x; i < 4096; i += 256) {
    sW[i] = Wb[i];
    int c = i >> 6, ll = i & 63;
    sA[c * 64 + ll] = Ab[(size_t)c * L + lt + ll];
  }
  __syncthreads();
  int l = threadIdx.x & 63, og = threadIdx.x >> 6;
  float acc[16];
#pragma unroll
  for (int j = 0; j < 16; ++j) acc[j] = 0.f;
  for (int c = 0; c < 64; ++c) {
    float av = sA[c * 64 + l];
#pragma unroll
    for (int j = 0; j < 16; ++j) acc[j] += sW[(og * 16 + j) * 64 + c] * av;
  }
#pragma unroll
  for (int j = 0; j < 16; ++j) {
    int o = og * 16 + j;
    float v = acc[j];
    if (RELU) v = fmaxf(v, 0.f);
    size_t idx = ((size_t)b * 64 + o) * L + lt + l;
    if (RES) v += res[idx];
    out[idx] = v;
  }
}

// ---- fused resize: M0[b,o,l] = sum_c pw[o,c] * dw5(Xcat)[b,c,l] ----------
__global__ __launch_bounds__(256) void k_resize(
    const float* __restrict__ Xcat, const float* __restrict__ dw,
    const float* __restrict__ pw, float* __restrict__ out) {
  __shared__ float sA[64 * 64];
  int b = blockIdx.x, lt = blockIdx.y * 64;
  int l = threadIdx.x & 63, og = threadIdx.x >> 6;
  float acc[16];
#pragma unroll
  for (int j = 0; j < 16; ++j) acc[j] = 0.f;
  for (int c0 = 0; c0 < 256; c0 += 64) {
    __syncthreads();
    for (int i = threadIdx.x; i < 4096; i += 256) {
      int c = (i >> 6) + c0, ll = (i & 63) + lt;
      const float* xr = Xcat + ((size_t)b * 256 + c) * 256;
      float a = 0.f;
#pragma unroll
      for (int k = 0; k < 5; ++k) {
        int p = ll + k - 2;
        if (p >= 0 && p < 256) a += xr[p] * dw[c * 5 + k];
      }
      sA[i] = a;
    }
    __syncthreads();
    for (int c = 0; c < 64; ++c) {
      float av = sA[c * 64 + l];
#pragma unroll
      for (int j = 0; j < 16; ++j)
        acc[j] += pw[(size_t)(og * 16 + j) * 256 + c0 + c] * av;
    }
  }
#pragma unroll
  for (int j = 0; j < 16; ++j)
    out[((size_t)b * 64 + og * 16 + j) * 256 + lt + l] = acc[j];
}

// ---------------- fused self-attention per (h,b) --------------------------
__global__ __launch_bounds__(256) void k_att(
    const float* __restrict__ t, const float* __restrict__ wq,
    const float* __restrict__ wk, const float* __restrict__ wv,
    float* __restrict__ hc, int L) {
  int h = blockIdx.x, b = blockIdx.y;
  __shared__ float sQ[8 * 256], sK[8 * 256], sV[8 * 256];
  __shared__ float swq[512], swk[512], swv[512];
  const float* tb = t + (size_t)b * 64 * L;
  size_t woff = (size_t)(h * B + b) * 512;
  for (int i = threadIdx.x; i < 512; i += 256) {
    swq[i] = wq[woff + i]; swk[i] = wk[woff + i]; swv[i] = wv[woff + i];
  }
  __syncthreads();
  for (int i = threadIdx.x; i < 8 * L; i += 256) {
    int k = i / L, l = i % L;
    float aq = 0.f, ak = 0.f, av = 0.f;
    for (int d = 0; d < 64; ++d) {
      float x = tb[d * L + l];
      aq += swq[k * 64 + d] * x;
      ak += swk[k * 64 + d] * x;
      av += swv[k * 64 + d] * x;
    }
    sQ[k * L + l] = aq; sK[k * L + l] = ak; sV[k * L + l] = av;
  }
  __syncthreads();
  const float scale = 0.35355339059327373f;  // 1/sqrt(8)
  for (int m = threadIdx.x; m < L; m += 256) {
    float kc[8];
#pragma unroll
    for (int k = 0; k < 8; ++k) kc[k] = sK[k * L + m];
    float mx = -1e30f;
    for (int l = 0; l < L; ++l) {
      float s = 0.f;
#pragma unroll
      for (int k = 0; k < 8; ++k) s += sQ[k * L + l] * kc[k];
      mx = fmaxf(mx, s * scale);
    }
    float sum = 0.f, acc[8];
#pragma unroll
    for (int v = 0; v < 8; ++v) acc[v] = 0.f;
    for (int l = 0; l < L; ++l) {
      float s = 0.f;
#pragma unroll
      for (int k = 0; k < 8; ++k) s += sQ[k * L + l] * kc[k];
      float p = __expf(s * scale - mx);
      sum += p;
#pragma unroll
      for (int v = 0; v < 8; ++v) acc[v] += p * sV[v * L + l];
    }
    float is = 1.f / sum;
    for (int v = 0; v < 8; ++v)
      hc[((size_t)b * 64 + h * 8 + v) * L + m] = acc[v] * is;
  }
}

// ---- fused char embed: gather + dw5x5 + pw(200->64) + relu + max over CN --
__global__ __launch_bounds__(256) void k_charembed(
    const int* __restrict__ cid, const float* __restrict__ ctab,
    const float* __restrict__ dw, const float* __restrict__ db,
    const float* __restrict__ pw, const float* __restrict__ pb,
    float* __restrict__ out, int Ln) {
  int n = blockIdx.x, b = blockIdx.y;
  __shared__ float dwo[200 * 16];
  __shared__ int sid[5][16];
  __shared__ float red[256];
  int tid = threadIdx.x;
  if (tid < 80) {
    int kn = tid / 16, cn = tid % 16;
    int nn = n + kn - 2;
    sid[kn][cn] = (nn >= 0 && nn < Ln) ? cid[((size_t)b * Ln + nn) * 16 + cn] : -1;
  }
  __syncthreads();
  for (int i = tid; i < 200 * 16; i += 256) {
    int ce = i / 16, cn = i % 16;
    float acc = db[ce];
    const float* wcc = dw + ce * 25;
#pragma unroll
    for (int kn = 0; kn < 5; ++kn)
#pragma unroll
      for (int kc = 0; kc < 5; ++kc) {
        int cc = cn + kc - 2;
        if (cc < 0 || cc >= 16) continue;
        int id = sid[kn][cc];
        if (id >= 0) acc += ctab[id * 200 + ce] * wcc[kn * 5 + kc];
      }
    dwo[i] = acc;
  }
  __syncthreads();
  int o = tid & 63, q = tid >> 6;
  float mx = -1e30f;
  const float* pwr = pw + o * 200;
  for (int cn = q; cn < 16; cn += 4) {
    float acc = pb[o];
    for (int ce = 0; ce < 200; ++ce) acc += pwr[ce] * dwo[ce * 16 + cn];
    mx = fmaxf(mx, acc);
  }
  red[tid] = mx;
  __syncthreads();
  if (q == 0) {
    mx = fmaxf(fmaxf(red[o], red[64 + o]), fmaxf(red[128 + o], red[192 + o]));
    out[((size_t)b * 64 + o) * Ln + n] = fmaxf(mx, 0.f);
  }
}

// ---- fused emb conv: [char(64); word(300)] -> dw5+b -> pw(364->64)+b -----
__global__ void k_embconv(const float* __restrict__ chx, const int* __restrict__ wid,
                          const float* __restrict__ wtab, const float* __restrict__ dw,
                          const float* __restrict__ db, const float* __restrict__ pw,
                          const float* __restrict__ pb, float* __restrict__ out, int Ln) {
  int n = blockIdx.x, b = blockIdx.y;
  __shared__ float dwc[EC];
  __shared__ int sw[5];
  int tid = threadIdx.x;
  if (tid < 5) {
    int nn = n + tid - 2;
    sw[tid] = (nn >= 0 && nn < Ln) ? wid[(size_t)b * Ln + nn] : -1;
  }
  __syncthreads();
  for (int ch = tid; ch < EC; ch += 64) {
    float acc = db[ch];
#pragma unroll
    for (int k = 0; k < 5; ++k) {
      int nn = n + k - 2;
      float v = 0.f;
      if (nn >= 0 && nn < Ln) {
        if (ch < 64) v = chx[((size_t)b * 64 + ch) * Ln + nn];
        else v = wtab[(size_t)sw[k] * 300 + (ch - 64)];
      }
      acc += v * dw[ch * 5 + k];
    }
    dwc[ch] = acc;
  }
  __syncthreads();
  int o = tid;
  float acc = pb[o];
  const float* pwr = pw + o * EC;
  for (int c = 0; c < EC; ++c) acc += pwr[c] * dwc[c];
  out[((size_t)b * 64 + o) * Ln + n] = acc;
}

// ---------------- highway -------------------------------------------------
__global__ void k_highway(const float* __restrict__ inx, const float* __restrict__ lw,
                          const float* __restrict__ lb, const float* __restrict__ gw,
                          const float* __restrict__ gb, float* __restrict__ out, int Ln) {
  int n = blockIdx.x, b = blockIdx.y;
  __shared__ float x[64], xn[64];
  int o = threadIdx.x;
  x[o] = inx[((size_t)b * 64 + o) * Ln + n];
  __syncthreads();
  for (int layer = 0; layer < 2; ++layer) {
    const float* lwr = lw + (layer * 64 + o) * 64;
    const float* gwr = gw + (layer * 64 + o) * 64;
    float gl = gb[layer * 64 + o], nl = lb[layer * 64 + o];
    for (int d = 0; d < 64; ++d) { gl += gwr[d] * x[d]; nl += lwr[d] * x[d]; }
    float g = 1.f / (1.f + __expf(-gl));
    float r = fmaxf(nl, 0.f);
    xn[o] = g * r + (1.f - g) * x[o];
    __syncthreads();
    x[o] = xn[o];
    __syncthreads();
  }
  out[((size_t)b * 64 + o) * Ln + n] = x[o];
}

// ---------------- context-query attention ---------------------------------
__global__ __launch_bounds__(256) void k_cqS(const float* __restrict__ C,
                                             const float* __restrict__ Q,
                                             const float* __restrict__ w,
                                             float* __restrict__ S) {
  int b = blockIdx.x, nt = blockIdx.y * 64;
  __shared__ float sQ[4096], sC[4096], ct[64], qt[64], swb[192];
  const float* Cb = C + (size_t)b * 64 * 256;
  const float* Qb = Q + (size_t)b * 4096;
  const float* wb = w + (size_t)b * 192;
  if (threadIdx.x < 192) swb[threadIdx.x] = wb[threadIdx.x];
  for (int i = threadIdx.x; i < 4096; i += 256) {
    int d = i >> 6, m = i & 63;
    sQ[i] = Qb[d * 64 + m];
    sC[i] = Cb[d * 256 + nt + m];
  }
  __syncthreads();
  if (threadIdx.x < 64) {
    int j = threadIdx.x;
    float a = 0.f, c2 = 0.f;
    for (int d = 0; d < 64; ++d) {
      a += swb[64 + d] * sC[d * 64 + j];   // wc . C
      c2 += swb[d] * sQ[d * 64 + j];       // wq . Q
    }
    ct[j] = a; qt[j] = c2;
  }
  __syncthreads();
  for (int i = threadIdx.x; i < 4096; i += 256) {
    int nl = i >> 6, m = i & 63;
    float acc = ct[nl] + qt[m];
    for (int d = 0; d < 64; ++d)
      acc += sC[d * 64 + nl] * swb[128 + d] * sQ[d * 64 + m];
    S[((size_t)b * 256 + nt + nl) * 64 + m] = acc;
  }
}

__global__ void k_cqrow(const float* __restrict__ S, float* __restrict__ rmax,
                        float* __restrict__ rsum) {
  int b = blockIdx.x, n = threadIdx.x;
  const float* Sr = S + ((size_t)b * 256 + n) * 64;
  float mx = -1e30f;
  for (int m = 0; m < 64; ++m) mx = fmaxf(mx, Sr[m]);
  float s = 0.f;
  for (int m = 0; m < 64; ++m) s += __expf(Sr[m] - mx);
  rmax[b * 256 + n] = mx; rsum[b * 256 + n] = s;
}

__global__ void k_cqcol(const float* __restrict__ S, float* __restrict__ cmax,
                        float* __restrict__ csum) {
  int b = blockIdx.x, m = threadIdx.x;
  const float* Sb = S + (size_t)b * 256 * 64;
  float mx = -1e30f;
  for (int n = 0; n < 256; ++n) mx = fmaxf(mx, Sb[n * 64 + m]);
  float s = 0.f;
  for (int n = 0; n < 256; ++n) s += __expf(Sb[n * 64 + m] - mx);
  cmax[b * 64 + m] = mx; csum[b * 64 + m] = s;
}

__global__ __launch_bounds__(256) void k_cqA(
    const float* __restrict__ C, const float* __restrict__ Q,
    const float* __restrict__ S, const float* __restrict__ rmax,
    const float* __restrict__ rsum, float* __restrict__ Xcat) {
  int b = blockIdx.x, nt = blockIdx.y * 64;
  __shared__ float sQ[4096];     // Q[d][m]
  __shared__ float sP[64 * 65];  // S1[nl][m]
  const float* Qb = Q + (size_t)b * 4096;
  for (int i = threadIdx.x; i < 4096; i += 256) sQ[i] = Qb[i];
  for (int i = threadIdx.x; i < 4096; i += 256) {
    int nl = i >> 6, m = i & 63;
    int n = nt + nl;
    sP[nl * 65 + m] = __expf(S[((size_t)b * 256 + n) * 64 + m] - rmax[b * 256 + n]) / rsum[b * 256 + n];
  }
  __syncthreads();
  int nl = threadIdx.x & 63, dg = threadIdx.x >> 6;
  int n = nt + nl;
  for (int j = 0; j < 16; ++j) {
    int d = dg * 16 + j;
    float acc = 0.f;
    for (int m = 0; m < 64; ++m) acc += sQ[d * 64 + m] * sP[nl * 65 + m];
    float cv = C[((size_t)b * 64 + d) * 256 + n];
    Xcat[((size_t)b * 256 + d) * 256 + n] = cv;
    Xcat[((size_t)b * 256 + 64 + d) * 256 + n] = acc;
    Xcat[((size_t)b * 256 + 128 + d) * 256 + n] = cv * acc;
  }
}

// CS2[d,m] = sum_n C[d,n] * S2[n,m]   (S2 = column softmax, cmax/csum)
__global__ __launch_bounds__(256) void k_cqCS2(
    const float* __restrict__ C, const float* __restrict__ S,
    const float* __restrict__ cmax, const float* __restrict__ csum,
    float* __restrict__ CS2) {
  int b = blockIdx.x;
  __shared__ float sP[4096], sC[4096];
  int m = threadIdx.x & 63, dg = threadIdx.x >> 6;
  float acc[16];
#pragma unroll
  for (int j = 0; j < 16; ++j) acc[j] = 0.f;
  for (int nt = 0; nt < 4; ++nt) {
    __syncthreads();
    for (int i = threadIdx.x; i < 4096; i += 256) {
      int nl = i >> 6, mm = i & 63;
      int n = nt * 64 + nl;
      sP[i] = __expf(S[((size_t)b * 256 + n) * 64 + mm] - cmax[b * 64 + mm]) / csum[b * 64 + mm];
      int d = i >> 6, nn = i & 63;
      sC[i] = C[((size_t)b * 64 + d) * 256 + nt * 64 + nn];
    }
    __syncthreads();
    for (int nl = 0; nl < 64; ++nl) {
      float p = sP[nl * 64 + m];
#pragma unroll
      for (int j = 0; j < 16; ++j) acc[j] += sC[(dg * 16 + j) * 64 + nl] * p;
    }
  }
  for (int j = 0; j < 16; ++j)
    CS2[((size_t)b * 64 + dg * 16 + j) * 64 + m] = acc[j];
}

// Bm[d,k] = sum_m CS2[d,m] * S1[k,m]   (S1 = row softmax at row k, rmax/rsum)
__global__ __launch_bounds__(256) void k_cqBm(
    const float* __restrict__ C, const float* __restrict__ CS2,
    const float* __restrict__ S, const float* __restrict__ rmax,
    const float* __restrict__ rsum, float* __restrict__ Xcat) {
  int b = blockIdx.x, kt = blockIdx.y * 64;
  __shared__ float sW[4096];     // CS2[d][m]
  __shared__ float sP[64 * 65];  // S1[kl][m]
  for (int i = threadIdx.x; i < 4096; i += 256) sW[i] = CS2[(size_t)b * 4096 + i];
  for (int i = threadIdx.x; i < 4096; i += 256) {
    int kl = i >> 6, m = i & 63;
    int k = kt + kl;
    sP[kl * 65 + m] = __expf(S[((size_t)b * 256 + k) * 64 + m] - rmax[b * 256 + k]) / rsum[b * 256 + k];
  }
  __syncthreads();
  int kl = threadIdx.x & 63, dg = threadIdx.x >> 6;
  int k = kt + kl;
  for (int j = 0; j < 16; ++j) {
    int d = dg * 16 + j;
    float acc = 0.f;
    for (int m = 0; m < 64; ++m) acc += sW[d * 64 + m] * sP[kl * 65 + m];
    float cv = C[((size_t)b * 64 + d) * 256 + k];
    Xcat[((size_t)b * 256 + 192 + d) * 256 + k] = cv * acc;
  }
}

// ---------------- pointer: Y = w . [Ma;Mb], softmax over n, fp32 out ------
__global__ void k_pointer(const float* __restrict__ Ma, const float* __restrict__ Mb2,
                          const float* __restrict__ w, float* __restrict__ out) {
  int b = blockIdx.x, n = threadIdx.x;
  const float* wb = w + b * 128;
  float y = 0.f;
  for (int d = 0; d < 64; ++d) {
    y += wb[d] * Ma[((size_t)b * 64 + d) * 256 + n];
    y += wb[64 + d] * Mb2[((size_t)b * 64 + d) * 256 + n];
  }
  __shared__ float wred[4], wsum[4];
  int lane = n & 63, wid = n >> 6;
  float mx = y;
#pragma unroll
  for (int o = 32; o > 0; o >>= 1) mx = fmaxf(mx, __shfl_xor(mx, o));
  if (lane == 0) wred[wid] = mx;
  __syncthreads();
  mx = fmaxf(fmaxf(wred[0], wred[1]), fmaxf(wred[2], wred[3]));
  float e = __expf(y - mx);
  float s = e;
#pragma unroll
  for (int o = 32; o > 0; o >>= 1) s += __shfl_xor(s, o);
  if (lane == 0) wsum[wid] = s;
  __syncthreads();
  s = wsum[0] + wsum[1] + wsum[2] + wsum[3];
  out[b * 256 + n] = e / s;
}

// ===========================================================================
extern "C" void kernel_launch(void* const* d_in, const int* in_sizes, int n_in,
                              void* d_out, int out_size, void* d_ws, size_t ws_size,
                              hipStream_t stream) {
  const float* word_table = (const float*)d_in[0];
  const float* char_table = (const float*)d_in[1];
  const float* e2dw = (const float*)d_in[2];
  const float* e2db = (const float*)d_in[3];
  const float* e2pw = (const float*)d_in[4];
  const float* e2pb = (const float*)d_in[5];
  const float* e1dw = (const float*)d_in[6];
  const float* e1db = (const float*)d_in[7];
  const float* e1pw = (const float*)d_in[8];
  const float* e1pb = (const float*)d_in[9];
  const float* hlw = (const float*)d_in[10];
  const float* hlb = (const float*)d_in[11];
  const float* hgw = (const float*)d_in[12];
  const float* hgb = (const float*)d_in[13];
  const float *enc_dw[5], *enc_pw[5], *enc_wq[5], *enc_wk[5], *enc_wv[5], *enc_wo[5], *enc_w[5];
  for (int p = 0; p < 5; ++p) {
    enc_dw[p] = (const float*)d_in[14 + 7 * p + 0];
    enc_pw[p] = (const float*)d_in[14 + 7 * p + 1];
    enc_wq[p] = (const float*)d_in[14 + 7 * p + 2];
    enc_wk[p] = (const float*)d_in[14 + 7 * p + 3];
    enc_wv[p] = (const float*)d_in[14 + 7 * p + 4];
    enc_wo[p] = (const float*)d_in[14 + 7 * p + 5];
    enc_w[p]  = (const float*)d_in[14 + 7 * p + 6];
  }
  const float* cq_w  = (const float*)d_in[49];
  const float* rs_dw = (const float*)d_in[50];
  const float* rs_pw = (const float*)d_in[51];
  const float* p_w0  = (const float*)d_in[52];
  const float* p_w1  = (const float*)d_in[53];
  const int* Cwid = (const int*)d_in[54];
  const int* Ccid = (const int*)d_in[55];
  const int* Qwid = (const int*)d_in[56];
  const int* Qcid = (const int*)d_in[57];
  float* out = (float*)d_out;

  // ---- compact workspace layout (floats), ~12.9 MB ------------------------
  float* ws = (float*)d_ws;
  const size_t SB = (size_t)B * 64 * 256;   // 393216
  float* postab = ws;                // 16384
  float* T    = ws + 16384;          // 393216 scratch
  float* U    = ws + 409600;         // 393216 scratch
  float* Xcat = ws + 802816;         // 1572864 ; M2 aliases after resize
  float* CX   = ws + 2375680;        // 393216  ; M0 aliases after cq
  float* Sb   = ws + 2768896;        // 393216  ; M1 aliases after cq
  float* QX   = ws + 3162112;        // 98304
  float* CS2  = ws + 3260416;        // 98304
  float* rmax = ws + 3358720;        // 6144
  float* rsum = ws + 3364864;        // 6144
  float* cmax = ws + 3371008;        // 1536
  float* csum = ws + 3372544;        // 1536
  float* M0 = CX; float* M1 = Sb; float* M2 = Xcat;
  (void)out_size; (void)in_sizes; (void)n_in; (void)ws_size;

  auto run_enc = [&](float* X, int L, int cnum, int K, int p) {
    int gb = (B * 64 * L + 255) / 256;
    k_posadd<<<gb, 256, 0, stream>>>(X, postab, L);
    for (int i = 0; i < cnum; ++i) {
      k_norm<<<B * 64, 64, 0, stream>>>(X, T, L);
      if (K == 7)
        hipLaunchKernelGGL((k_dwconv<7>), dim3(gb), dim3(256), 0, stream, T, U, enc_dw[p] + i * 64 * 7, L);
      else
        hipLaunchKernelGGL((k_dwconv<5>), dim3(gb), dim3(256), 0, stream, T, U, enc_dw[p] + i * 64 * 5, L);
      hipLaunchKernelGGL((k_matmul<true, true, false>), dim3(B, L / 64), dim3(256), 0, stream,
                         U, enc_pw[p] + (size_t)i * 4096, (const float*)X, X, L);
    }
    k_norm<<<B * 64, 64, 0, stream>>>(X, T, L);
    k_att<<<dim3(HH, B), 256, 0, stream>>>(T, enc_wq[p], enc_wk[p], enc_wv[p], U, L);
    hipLaunchKernelGGL((k_matmul<false, true, true>), dim3(B, L / 64), dim3(256), 0, stream,
                       U, enc_wo[p], (const float*)X, X, L);
    k_norm<<<B * 64, 64, 0, stream>>>(X, T, L);
    hipLaunchKernelGGL((k_matmul<true, true, true>), dim3(B, L / 64), dim3(256), 0, stream,
                       T, enc_w[p], (const float*)X, X, L);
  };

  k_postab<<<64, 256, 0, stream>>>(postab);
  // ---- embeddings ----
  k_charembed<<<dim3(NN, B), 256, 0, stream>>>(Ccid, char_table, e2dw, e2db, e2pw, e2pb, T, NN);
  k_embconv<<<dim3(NN, B), 64, 0, stream>>>(T, Cwid, word_table, e1dw, e1db, e1pw, e1pb, U, NN);
  k_highway<<<dim3(NN, B), 64, 0, stream>>>(U, hlw, hlb, hgw, hgb, CX, NN);
  k_charembed<<<dim3(MQ, B), 256, 0, stream>>>(Qcid, char_table, e2dw, e2db, e2pw, e2pb, T, MQ);
  k_embconv<<<dim3(MQ, B), 64, 0, stream>>>(T, Qwid, word_table, e1dw, e1db, e1pw, e1pb, U, MQ);
  k_highway<<<dim3(MQ, B), 64, 0, stream>>>(U, hlw, hlb, hgw, hgb, QX, MQ);
  // ---- embedding encoders ----
  run_enc(CX, 256, 4, 7, 0);
  run_enc(QX, 64, 4, 7, 1);
  // ---- context-query attention ----
  k_cqS<<<dim3(B, 4), 256, 0, stream>>>(CX, QX, cq_w, Sb);
  k_cqrow<<<B, 256, 0, stream>>>(Sb, rmax, rsum);
  k_cqcol<<<B, 64, 0, stream>>>(Sb, cmax, csum);
  k_cqA<<<dim3(B, 4), 256, 0, stream>>>(CX, QX, Sb, rmax, rsum, Xcat);
  k_cqCS2<<<B, 256, 0, stream>>>(CX, Sb, cmax, csum, CS2);
  k_cqBm<<<dim3(B, 4), 256, 0, stream>>>(CX, CS2, Sb, rmax, rsum, Xcat);
  // ---- fused resize conv (dw5 + pw 256->64) -> M0 ----
  k_resize<<<dim3(B, 4), 256, 0, stream>>>(Xcat, rs_dw, rs_pw, M0);
  // ---- model encoders ----
  for (int r = 0; r < 7; ++r) run_enc(M0, 256, 2, 5, 2);
  hipMemcpyAsync(M1, M0, SB * sizeof(float), hipMemcpyDeviceToDevice, stream);
  for (int r = 0; r < 7; ++r) run_enc(M1, 256, 2, 5, 3);
  hipMemcpyAsync(M2, M1, SB * sizeof(float), hipMemcpyDeviceToDevice, stream);
  for (int r = 0; r < 7; ++r) run_enc(M2, 256, 2, 5, 4);
  // ---- pointers ----
  k_pointer<<<B, 256, 0, stream>>>(M0, M1, p_w0, out);
  k_pointer<<<B, 256, 0, stream>>>(M0, M2, p_w1, out + 6144);
}